// Round 8
// baseline (201.823 us; speedup 1.0000x reference)
//
#include <hip/hip_runtime.h>
#include <hip/hip_bf16.h>
#include <stdint.h>

#define D 128

using bf16x8 = __attribute__((ext_vector_type(8))) short;
using f32x4  = __attribute__((ext_vector_type(4))) float;

__device__ __forceinline__ unsigned short f2bf(float f) {
    unsigned u = __float_as_uint(f);
    u = (u + 0x7fffu + ((u >> 16) & 1u)) >> 16;   // RNE
    return (unsigned short)u;
}
__device__ __forceinline__ float bf2f(unsigned short h) {
    return __uint_as_float(((unsigned)h) << 16);
}

// 8 fp32 -> 8 bf16 via packed HW cvt (RNE)
__device__ __forceinline__ bf16x8 cvt8(float4 a, float4 b) {
    union { bf16x8 v; __hip_bfloat162 h[4]; } u;
    u.h[0] = __float22bfloat162_rn(make_float2(a.x, a.y));
    u.h[1] = __float22bfloat162_rn(make_float2(a.z, a.w));
    u.h[2] = __float22bfloat162_rn(make_float2(b.x, b.y));
    u.h[3] = __float22bfloat162_rn(make_float2(b.z, b.w));
    return u.v;
}

// pack two f32x4 accumulators -> 8 bf16 (16 B)
__device__ __forceinline__ uint4 pack2(f32x4 x, f32x4 y) {
    union { uint4 u; __hip_bfloat162 h[4]; } o;
    o.h[0] = __float22bfloat162_rn(make_float2(x[0], x[1]));
    o.h[1] = __float22bfloat162_rn(make_float2(x[2], x[3]));
    o.h[2] = __float22bfloat162_rn(make_float2(y[0], y[1]));
    o.h[3] = __float22bfloat162_rn(make_float2(y[2], y[3]));
    return o.u;
}

// ---------- prep: Wt[r][c][k] = bf16(W[r][k][c]) only ----------
__global__ __launch_bounds__(256) void prep_wt_kernel(
    const float* __restrict__ W, unsigned short* __restrict__ Wt, int total)
{
    int idx = blockIdx.x * 256 + threadIdx.x;
    if (idx >= total) return;
    int r = idx >> 14;            // /(D*D)
    int rem = idx & 16383;
    int k = rem >> 7, c = rem & 127;
    Wt[(r << 14) + (c << 7) + k] = f2bf(W[idx]);
}

// ---------- fused Phase 1 + degree count ----------
// Blocks [0,tBlocks): transform — H[r][n][perm(c)] = bf16(feat[n][:] @ W[r]).
//   Wt[rel] staged once into XOR-swizzled LDS (one barrier), A-frags via
//   conflict-free ds_read_b128, B-frags from fp32 feat (L3-hot, cvt inline),
//   permuted sector-aligned uint4 stores.
// Blocks [tBlocks,...): degree count — latency-bound memory-side atomics,
//   co-scheduled with (and hidden under) the throughput-bound transform.
__global__ __launch_bounds__(256) void fused_transform_count_kernel(
    const float* __restrict__ feat, const unsigned short* __restrict__ Wt,
    unsigned short* __restrict__ H,
    const int* __restrict__ dst, int* __restrict__ deg, int* __restrict__ ord,
    int N, int NBX, int tBlocks, int E)
{
    __shared__ __align__(16) unsigned short sW[128 * 128];   // 32 KB
    const int b = blockIdx.x;

    if (b >= tBlocks) {
        // ---- degree count branch ----
        int e = (b - tBlocks) * 256 + threadIdx.x;
        if (e < E) ord[e] = atomicAdd(&deg[dst[e]], 1);
        return;
    }

    // ---- transform branch ----
    const int rel = b / NBX;
    const int bx  = b - rel * NBX;
    const int tid  = threadIdx.x;
    const int wave = tid >> 6, lane = tid & 63;
    const int q    = lane >> 4, mlo = lane & 15;

    // stage Wt[rel] -> LDS, swizzled: row c, 16B chunk ch at (ch ^ (c&15))
    {
        const ulonglong2* wsrc = (const ulonglong2*)(Wt + ((size_t)rel << 14));
        #pragma unroll
        for (int i = 0; i < 8; ++i) {
            int idx = tid + 256 * i;           // 0..2047
            int row = idx >> 4, ch = idx & 15;
            ulonglong2 v = wsrc[idx];
            *(ulonglong2*)&sW[row * 128 + ((ch ^ (row & 15)) * 8)] = v;
        }
    }

    // B-frags: 2 groups of 16 nodes; B[k=ks*32+q*8+j][n=mlo]; fp32 feat + cvt
    const int nb = bx * 128 + wave * 32;
    bf16x8 bfr[2][4];
    int nodeg[2];
    #pragma unroll
    for (int g = 0; g < 2; ++g) {
        int node = nb + g * 16 + mlo;
        nodeg[g] = node;
        int ld = node < N ? node : N - 1;
        const float* fp = feat + (size_t)ld * D + q * 8;
        #pragma unroll
        for (int ks = 0; ks < 4; ++ks)
            bfr[g][ks] = cvt8(*(const float4*)(fp + ks * 32), *(const float4*)(fp + ks * 32 + 4));
    }
    __syncthreads();

    const size_t Hb = (size_t)rel * N * D;
    unsigned short* hp0 = H + Hb + (size_t)nodeg[0] * D + q * 8;
    unsigned short* hp1 = H + Hb + (size_t)nodeg[1] * D + q * 8;

    #pragma unroll
    for (int j = 0; j < 4; ++j) {
        // A-frags for ct = 2j, 2j+1 from LDS (conflict-free swizzle)
        bf16x8 af0[4], af1[4];
        const int row0 = (2 * j) * 16 + mlo, row1 = row0 + 16;
        #pragma unroll
        for (int ks = 0; ks < 4; ++ks) {
            af0[ks] = *(const bf16x8*)&sW[row0 * 128 + (((ks * 4 + q) ^ mlo) * 8)];
            af1[ks] = *(const bf16x8*)&sW[row1 * 128 + (((ks * 4 + q) ^ mlo) * 8)];
        }
        #pragma unroll
        for (int g = 0; g < 2; ++g) {
            f32x4 a = {0.f,0.f,0.f,0.f}, c = {0.f,0.f,0.f,0.f};
            #pragma unroll
            for (int ks = 0; ks < 4; ++ks) {
                a = __builtin_amdgcn_mfma_f32_16x16x32_bf16(af0[ks], bfr[g][ks], a, 0, 0, 0);
                c = __builtin_amdgcn_mfma_f32_16x16x32_bf16(af1[ks], bfr[g][ks], c, 0, 0, 0);
            }
            if (nodeg[g] < N)
                *(uint4*)((g ? hp1 : hp0) + j * 32) = pack2(a, c);
        }
    }
}

// ---------- CSR scan kernels ----------
__global__ __launch_bounds__(256) void k_blocksum(
    const int* __restrict__ deg, int* __restrict__ part, int N)
{
    int t = threadIdx.x, i = blockIdx.x * 256 + t;
    int v = (i < N) ? deg[i] : 0;
    #pragma unroll
    for (int o = 32; o > 0; o >>= 1) v += __shfl_down(v, o, 64);
    __shared__ int ws_[4];
    if ((t & 63) == 0) ws_[t >> 6] = v;
    __syncthreads();
    if (t == 0) part[blockIdx.x] = ws_[0] + ws_[1] + ws_[2] + ws_[3];
}

__global__ __launch_bounds__(256) void k_scanpart(int* part, int nb)
{
    __shared__ int s[256];
    int t = threadIdx.x;
    int v = (t < nb) ? part[t] : 0;
    s[t] = v;
    #pragma unroll
    for (int o = 1; o < 256; o <<= 1) {
        __syncthreads();
        int x = (t >= o) ? s[t - o] : 0;
        __syncthreads();
        s[t] += x;
    }
    if (t < nb) part[t] = s[t] - v;
}

__global__ __launch_bounds__(256) void k_scanfinal(
    const int* __restrict__ deg, const int* __restrict__ part,
    int* __restrict__ off, int N, int E)
{
    __shared__ int s[256];
    int t = threadIdx.x, i = blockIdx.x * 256 + t;
    int v = (i < N) ? deg[i] : 0;
    s[t] = v;
    #pragma unroll
    for (int o = 1; o < 256; o <<= 1) {
        __syncthreads();
        int x = (t >= o) ? s[t - o] : 0;
        __syncthreads();
        s[t] += x;
    }
    if (i < N) off[i] = part[blockIdx.x] + s[t] - v;
    if (i == 0) off[N] = E;
}

// fill: sorted[] holds precomputed H BYTE offsets ((et*N+src)*256)
__global__ __launch_bounds__(256) void k_fill(
    const int* __restrict__ dst, const int* __restrict__ et,
    const int* __restrict__ src, const int* __restrict__ off,
    const int* __restrict__ ord, unsigned int* __restrict__ sorted, int E, int N)
{
    int e = blockIdx.x * 256 + threadIdx.x;
    if (e >= E) return;
    unsigned key = ((unsigned)et[e] * (unsigned)N + (unsigned)src[e]) << 8;
    sorted[off[dst[e]] + ord[e]] = key;
}

// ---------- Phase 2: gather. 1 node per wave; 16-deep predicated pipeline;
// sorted[] holds H byte-offsets. Channel map f matches transform layout. ----------
__global__ __launch_bounds__(256) void k_gather4(
    const char* __restrict__ Hc, const unsigned int* __restrict__ sorted,
    const int* __restrict__ off, const float* __restrict__ feat,
    float* __restrict__ out, int N)
{
    int n = blockIdx.x * 4 + (threadIdx.x >> 6);
    if (n >= N) return;
    int lane = threadIdx.x & 63;

    // permuted channel-pair index (matches transform slot layout)
    const int jj = lane >> 4, qq = (lane >> 2) & 3, pp = lane & 3;
    const int f = 16 * jj + 8 * (pp >> 1) + 2 * qq + (pp & 1);

    float2 acc = ((const float2*)feat)[(size_t)n * 64 + f];   // (1+eps)*h

    int j0 = __builtin_amdgcn_readfirstlane(off[n]);
    int j1 = __builtin_amdgcn_readfirstlane(off[n + 1]);
    int deg = j1 - j0;
    if (deg > 0) {
        unsigned ep = sorted[j0 + (lane < deg ? lane : deg - 1)];
        int capped = deg < 64 ? deg : 64;
        for (int done = 0; done < capped; done += 16) {
            unsigned a[16];
            #pragma unroll
            for (int u = 0; u < 16; ++u) {
                int idx = done + u; idx = idx < capped ? idx : capped - 1;
                unsigned p = __shfl(ep, idx);
                a[u] = *(const unsigned*)(Hc + p + lane * 4);
            }
            #pragma unroll
            for (int u = 0; u < 16; ++u) {
                bool v = (done + u) < capped;
                acc.x += v ? bf2f((unsigned short)(a[u] & 0xffffu)) : 0.f;
                acc.y += v ? bf2f((unsigned short)(a[u] >> 16)) : 0.f;
            }
        }
        for (int j = j0 + 64; j < j1; ++j) {   // rare high-degree tail
            unsigned p = sorted[j];
            unsigned a0 = *(const unsigned*)(Hc + p + lane * 4);
            acc.x += bf2f((unsigned short)(a0 & 0xffffu));
            acc.y += bf2f((unsigned short)(a0 >> 16));
        }
    }
    ((float2*)out)[(size_t)n * 64 + f] = acc;
}

// ---------- fallbacks ----------
__global__ __launch_bounds__(256) void init_kernel(
    const float* __restrict__ feat, float* __restrict__ out, int n4)
{
    int i = blockIdx.x * 256 + threadIdx.x;
    if (i < n4) ((float4*)out)[i] = ((const float4*)feat)[i];
}

__global__ __launch_bounds__(128) void edge_matvec_kernel(
    const float* __restrict__ feat, const float* __restrict__ W,
    const int* __restrict__ et, const int* __restrict__ src,
    const int* __restrict__ dst, float* __restrict__ out, int E)
{
    __shared__ float xs[D];
    int e = blockIdx.x;
    int c = threadIdx.x;
    int s = src[e], r = et[e], d = dst[e];
    xs[c] = feat[(size_t)s * D + c];
    __syncthreads();
    const float* Wr = W + (size_t)r * D * D;
    float acc = 0.f;
    #pragma unroll 8
    for (int k = 0; k < D; ++k) acc += xs[k] * Wr[(size_t)k * D + c];
    atomicAdd(out + (size_t)d * D + c, acc);
}

static inline size_t al256(size_t x) { return (x + 255) & ~(size_t)255; }

extern "C" void kernel_launch(void* const* d_in, const int* in_sizes, int n_in,
                              void* d_out, int out_size, void* d_ws, size_t ws_size,
                              hipStream_t stream) {
    const float* feat = (const float*)d_in[0];
    const float* W    = (const float*)d_in[1];
    const int*   et   = (const int*)d_in[2];
    const int*   src  = (const int*)d_in[3];
    const int*   dst  = (const int*)d_in[4];
    float* out = (float*)d_out;

    const int N = in_sizes[0] / D;
    const int R = in_sizes[1] / (D * D);
    const int E = in_sizes[2];

    size_t hB   = al256((size_t)R * N * D * sizeof(unsigned short));
    size_t wtB  = al256((size_t)R * D * D * sizeof(unsigned short));
    size_t offB = al256((size_t)(N + 1) * sizeof(int));
    size_t degB = al256((size_t)N * sizeof(int));
    size_t ordB = al256((size_t)E * sizeof(int));
    size_t parB = al256(1024 * sizeof(int));
    size_t srtB = al256((size_t)E * sizeof(unsigned int));
    size_t need = hB + wtB + offB + degB + ordB + parB + srtB;

    const int nbScan = (N + 255) / 256;
    const bool packable = (nbScan <= 256) &&
                          ((size_t)R * (size_t)N * 256ull <= 0xFFFFFFFFull);

    if (ws_size >= need && packable) {
        char* p = (char*)d_ws;
        unsigned short* H      = (unsigned short*)p;           p += hB;
        unsigned short* Wt     = (unsigned short*)p;           p += wtB;
        int*            off    = (int*)p;                      p += offB;
        int*            deg    = (int*)p;                      p += degB;
        int*            ord    = (int*)p;                      p += ordB;
        int*            part   = (int*)p;                      p += parB;
        unsigned int*   sorted = (unsigned int*)p;

        int wtTotal = R * D * D;
        int cntBlocks = (E + 255) / 256;

        hipMemsetAsync(deg, 0, (size_t)N * sizeof(int), stream);
        prep_wt_kernel<<<(wtTotal + 255) / 256, 256, 0, stream>>>(W, Wt, wtTotal);

        // Fused: transform (throughput-bound) + degree count (latency-bound)
        int NBX = (N + 127) / 128;
        int tBlocks = NBX * R;
        fused_transform_count_kernel<<<tBlocks + cntBlocks, 256, 0, stream>>>(
            feat, Wt, H, dst, deg, ord, N, NBX, tBlocks, E);

        // CSR build (by dst)
        k_blocksum<<<nbScan, 256, 0, stream>>>(deg, part, N);
        k_scanpart<<<1, 256, 0, stream>>>(part, nbScan);
        k_scanfinal<<<nbScan, 256, 0, stream>>>(deg, part, off, N, E);
        k_fill<<<cntBlocks, 256, 0, stream>>>(dst, et, src, off, ord, sorted, E, N);

        // Phase 2: gather-sum, 1 node/wave, 16-deep pipeline
        k_gather4<<<(N + 3) / 4, 256, 0, stream>>>((const char*)H, sorted, off, feat, out, N);
    } else {
        int n4 = (N * D) / 4;
        init_kernel<<<(n4 + 255) / 256, 256, 0, stream>>>(feat, out, n4);
        edge_matvec_kernel<<<E, 128, 0, stream>>>(feat, W, et, src, dst, out, E);
    }
}

// Round 9
// 178.853 us; speedup vs baseline: 1.1284x; 1.1284x over previous
//
#include <hip/hip_runtime.h>
#include <hip/hip_bf16.h>
#include <stdint.h>

#define D 128

using bf16x8 = __attribute__((ext_vector_type(8))) short;
using f32x4  = __attribute__((ext_vector_type(4))) float;

__device__ __forceinline__ unsigned short f2bf(float f) {
    unsigned u = __float_as_uint(f);
    u = (u + 0x7fffu + ((u >> 16) & 1u)) >> 16;   // RNE
    return (unsigned short)u;
}
__device__ __forceinline__ float bf2f(unsigned short h) {
    return __uint_as_float(((unsigned)h) << 16);
}

__device__ __forceinline__ bf16x8 cvt8(float4 a, float4 b) {
    union { bf16x8 v; __hip_bfloat162 h[4]; } u;
    u.h[0] = __float22bfloat162_rn(make_float2(a.x, a.y));
    u.h[1] = __float22bfloat162_rn(make_float2(a.z, a.w));
    u.h[2] = __float22bfloat162_rn(make_float2(b.x, b.y));
    u.h[3] = __float22bfloat162_rn(make_float2(b.z, b.w));
    return u.v;
}

__device__ __forceinline__ uint4 pack2(f32x4 x, f32x4 y) {
    union { uint4 u; __hip_bfloat162 h[4]; } o;
    o.h[0] = __float22bfloat162_rn(make_float2(x[0], x[1]));
    o.h[1] = __float22bfloat162_rn(make_float2(x[2], x[3]));
    o.h[2] = __float22bfloat162_rn(make_float2(y[0], y[1]));
    o.h[3] = __float22bfloat162_rn(make_float2(y[2], y[3]));
    return o.u;
}

// ---------- prep2: featb cast + Wt transpose (NO count) ----------
__global__ __launch_bounds__(256) void prep2_kernel(
    const float* __restrict__ feat, unsigned short* __restrict__ featb,
    const float* __restrict__ W, unsigned short* __restrict__ Wt,
    int fcTotal /*chunks of 8*/, int wtTotal)
{
    int fcBlocks = (fcTotal + 255) >> 8;
    int b = blockIdx.x;
    if (b < fcBlocks) {
        int i = b * 256 + threadIdx.x;
        if (i < fcTotal) {
            const float4* p = (const float4*)feat + (size_t)i * 2;
            *(bf16x8*)(featb + (size_t)i * 8) = cvt8(p[0], p[1]);
        }
    } else {
        int idx = (b - fcBlocks) * 256 + threadIdx.x;
        if (idx < wtTotal) {
            int r = idx >> 14;
            int rem = idx & 16383;
            int k = rem >> 7, c = rem & 127;
            Wt[(r << 14) + (c << 7) + k] = f2bf(W[idx]);
        }
    }
}

// ---------- fused: transform (featb) + degree count, Bresenham-interleaved ----------
// transform: H[r][n][perm(c)] = bf16(featb[n][:] @ W[r]); Wt[rel] staged once
// into XOR-swizzled LDS (one barrier), conflict-free ds_read_b128 A-frags,
// permuted sector-aligned uint4 stores.
// count: latency-bound memory-side atomics, interleaved so both kinds of
// blocks are co-resident from the start (r8 put count blocks last -> serial).
__global__ __launch_bounds__(256) void fused2_kernel(
    const unsigned short* __restrict__ featb, const unsigned short* __restrict__ Wt,
    unsigned short* __restrict__ H,
    const int* __restrict__ dst, int* __restrict__ deg, int* __restrict__ ord,
    int N, int NBX, int tBlocks, int cntBlocks, int E)
{
    __shared__ __align__(16) unsigned short sW[128 * 128];   // 32 KB
    const int b = blockIdx.x;
    const long long total = (long long)tBlocks + cntBlocks;

    // Bresenham role assignment: spreads count blocks evenly through launch order
    long long cb = ((long long)b * cntBlocks) / total;
    bool isCount = (((long long)(b + 1) * cntBlocks) / total) > cb;

    if (isCount) {
        int e = (int)cb * 256 + threadIdx.x;
        if (e < E) ord[e] = atomicAdd(&deg[dst[e]], 1);
        return;
    }

    const int tIdx = b - (int)cb;
    const int rel = tIdx / NBX;
    const int bx  = tIdx - rel * NBX;
    const int tid  = threadIdx.x;
    const int wave = tid >> 6, lane = tid & 63;
    const int q    = lane >> 4, mlo = lane & 15;

    // stage Wt[rel] -> LDS, swizzled: row c, 16B chunk ch at (ch ^ (c&15))
    {
        const ulonglong2* wsrc = (const ulonglong2*)(Wt + ((size_t)rel << 14));
        #pragma unroll
        for (int i = 0; i < 8; ++i) {
            int idx = tid + 256 * i;           // 0..2047
            int row = idx >> 4, ch = idx & 15;
            ulonglong2 v = wsrc[idx];
            *(ulonglong2*)&sW[row * 128 + ((ch ^ (row & 15)) * 8)] = v;
        }
    }

    // B-frags: 2 groups of 16 nodes; B[k=ks*32+q*8+j][n=mlo]
    const int nb = bx * 128 + wave * 32;
    bf16x8 bfr[2][4];
    int nodeg[2];
    #pragma unroll
    for (int g = 0; g < 2; ++g) {
        int node = nb + g * 16 + mlo;
        nodeg[g] = node;
        int ld = node < N ? node : N - 1;
        const unsigned short* fp = featb + (size_t)ld * D + q * 8;
        #pragma unroll
        for (int ks = 0; ks < 4; ++ks)
            bfr[g][ks] = *(const bf16x8*)(fp + ks * 32);
    }
    __syncthreads();

    const size_t Hb = (size_t)rel * N * D;
    unsigned short* hp0 = H + Hb + (size_t)nodeg[0] * D + q * 8;
    unsigned short* hp1 = H + Hb + (size_t)nodeg[1] * D + q * 8;

    #pragma unroll
    for (int j = 0; j < 4; ++j) {
        bf16x8 af0[4], af1[4];
        const int row0 = (2 * j) * 16 + mlo, row1 = row0 + 16;
        #pragma unroll
        for (int ks = 0; ks < 4; ++ks) {
            af0[ks] = *(const bf16x8*)&sW[row0 * 128 + (((ks * 4 + q) ^ mlo) * 8)];
            af1[ks] = *(const bf16x8*)&sW[row1 * 128 + (((ks * 4 + q) ^ mlo) * 8)];
        }
        #pragma unroll
        for (int g = 0; g < 2; ++g) {
            f32x4 a = {0.f,0.f,0.f,0.f}, c = {0.f,0.f,0.f,0.f};
            #pragma unroll
            for (int ks = 0; ks < 4; ++ks) {
                a = __builtin_amdgcn_mfma_f32_16x16x32_bf16(af0[ks], bfr[g][ks], a, 0, 0, 0);
                c = __builtin_amdgcn_mfma_f32_16x16x32_bf16(af1[ks], bfr[g][ks], c, 0, 0, 0);
            }
            if (nodeg[g] < N)
                *(uint4*)((g ? hp1 : hp0) + j * 32) = pack2(a, c);
        }
    }
}

// ---------- CSR scan kernels ----------
__global__ __launch_bounds__(256) void k_blocksum(
    const int* __restrict__ deg, int* __restrict__ part, int N)
{
    int t = threadIdx.x, i = blockIdx.x * 256 + t;
    int v = (i < N) ? deg[i] : 0;
    #pragma unroll
    for (int o = 32; o > 0; o >>= 1) v += __shfl_down(v, o, 64);
    __shared__ int ws_[4];
    if ((t & 63) == 0) ws_[t >> 6] = v;
    __syncthreads();
    if (t == 0) part[blockIdx.x] = ws_[0] + ws_[1] + ws_[2] + ws_[3];
}

__global__ __launch_bounds__(256) void k_scanpart(int* part, int nb)
{
    __shared__ int s[256];
    int t = threadIdx.x;
    int v = (t < nb) ? part[t] : 0;
    s[t] = v;
    #pragma unroll
    for (int o = 1; o < 256; o <<= 1) {
        __syncthreads();
        int x = (t >= o) ? s[t - o] : 0;
        __syncthreads();
        s[t] += x;
    }
    if (t < nb) part[t] = s[t] - v;
}

__global__ __launch_bounds__(256) void k_scanfinal(
    const int* __restrict__ deg, const int* __restrict__ part,
    int* __restrict__ off, int N, int E)
{
    __shared__ int s[256];
    int t = threadIdx.x, i = blockIdx.x * 256 + t;
    int v = (i < N) ? deg[i] : 0;
    s[t] = v;
    #pragma unroll
    for (int o = 1; o < 256; o <<= 1) {
        __syncthreads();
        int x = (t >= o) ? s[t - o] : 0;
        __syncthreads();
        s[t] += x;
    }
    if (i < N) off[i] = part[blockIdx.x] + s[t] - v;
    if (i == 0) off[N] = E;
}

// fill: sorted[] holds precomputed H BYTE offsets ((et*N+src)*256)
__global__ __launch_bounds__(256) void k_fill(
    const int* __restrict__ dst, const int* __restrict__ et,
    const int* __restrict__ src, const int* __restrict__ off,
    const int* __restrict__ ord, unsigned int* __restrict__ sorted, int E, int N)
{
    int e = blockIdx.x * 256 + threadIdx.x;
    if (e >= E) return;
    unsigned key = ((unsigned)et[e] * (unsigned)N + (unsigned)src[e]) << 8;
    sorted[off[dst[e]] + ord[e]] = key;
}

// ---------- Phase 2: gather. 1 node/wave; 8-B lane loads (32 lanes/row) so
// each load instr covers TWO edges (halves take even/odd edges); 16-deep
// pipeline = 32 edges in flight; halves combined via shfl(lane^32);
// channel map matches transform's permuted H layout; float4 final store. ----------
__global__ __launch_bounds__(256) void k_gather5(
    const char* __restrict__ Hc, const unsigned int* __restrict__ sorted,
    const int* __restrict__ off, const float* __restrict__ feat,
    float* __restrict__ out, int N)
{
    int n = blockIdx.x * 4 + (threadIdx.x >> 6);
    if (n >= N) return;
    int lane = threadIdx.x & 63;
    int h = lane >> 5, l5 = lane & 31;

    float2 acc0 = {0.f, 0.f}, acc1 = {0.f, 0.f};

    int j0 = __builtin_amdgcn_readfirstlane(off[n]);
    int j1 = __builtin_amdgcn_readfirstlane(off[n + 1]);
    int deg = j1 - j0;
    if (deg > 0) {
        int capped = deg < 64 ? deg : 64;
        unsigned ep = sorted[j0 + (lane < deg ? lane : deg - 1)];
        for (int done = 0; done < capped; done += 32) {
            unsigned long long a[16];
            #pragma unroll
            for (int u = 0; u < 16; ++u) {
                int eidx = done + 2 * u + h;
                int cl = eidx < capped ? eidx : capped - 1;
                unsigned p = __shfl(ep, cl);
                a[u] = *(const unsigned long long*)(Hc + p + l5 * 8);
            }
            #pragma unroll
            for (int u = 0; u < 16; ++u) {
                bool v = (done + 2 * u + h) < capped;
                unsigned lo = (unsigned)a[u], hi = (unsigned)(a[u] >> 32);
                acc0.x += v ? bf2f((unsigned short)(lo & 0xffffu)) : 0.f;
                acc0.y += v ? bf2f((unsigned short)(lo >> 16)) : 0.f;
                acc1.x += v ? bf2f((unsigned short)(hi & 0xffffu)) : 0.f;
                acc1.y += v ? bf2f((unsigned short)(hi >> 16)) : 0.f;
            }
        }
        for (int j = j0 + 64 + h; j < j1; j += 2) {   // rare high-degree tail
            unsigned p = sorted[j];
            unsigned long long a0 = *(const unsigned long long*)(Hc + p + l5 * 8);
            unsigned lo = (unsigned)a0, hi = (unsigned)(a0 >> 32);
            acc0.x += bf2f((unsigned short)(lo & 0xffffu));
            acc0.y += bf2f((unsigned short)(lo >> 16));
            acc1.x += bf2f((unsigned short)(hi & 0xffffu));
            acc1.y += bf2f((unsigned short)(hi >> 16));
        }
    }
    // combine halves
    acc0.x += __shfl(acc0.x, lane ^ 32);
    acc0.y += __shfl(acc0.y, lane ^ 32);
    acc1.x += __shfl(acc1.x, lane ^ 32);
    acc1.y += __shfl(acc1.y, lane ^ 32);
    if (h == 0) {
        // float4 channel index for this lane's 8-B H granule (permuted layout)
        int f4 = 8 * (l5 >> 3) + 4 * (l5 & 1) + ((l5 >> 1) & 3);
        float4 fv = ((const float4*)feat)[(size_t)n * 32 + f4];
        float4 o;
        o.x = fv.x + acc0.x; o.y = fv.y + acc0.y;
        o.z = fv.z + acc1.x; o.w = fv.w + acc1.y;
        ((float4*)out)[(size_t)n * 32 + f4] = o;
    }
}

// ---------- fallbacks ----------
__global__ __launch_bounds__(256) void init_kernel(
    const float* __restrict__ feat, float* __restrict__ out, int n4)
{
    int i = blockIdx.x * 256 + threadIdx.x;
    if (i < n4) ((float4*)out)[i] = ((const float4*)feat)[i];
}

__global__ __launch_bounds__(128) void edge_matvec_kernel(
    const float* __restrict__ feat, const float* __restrict__ W,
    const int* __restrict__ et, const int* __restrict__ src,
    const int* __restrict__ dst, float* __restrict__ out, int E)
{
    __shared__ float xs[D];
    int e = blockIdx.x;
    int c = threadIdx.x;
    int s = src[e], r = et[e], d = dst[e];
    xs[c] = feat[(size_t)s * D + c];
    __syncthreads();
    const float* Wr = W + (size_t)r * D * D;
    float acc = 0.f;
    #pragma unroll 8
    for (int k = 0; k < D; ++k) acc += xs[k] * Wr[(size_t)k * D + c];
    atomicAdd(out + (size_t)d * D + c, acc);
}

static inline size_t al256(size_t x) { return (x + 255) & ~(size_t)255; }

extern "C" void kernel_launch(void* const* d_in, const int* in_sizes, int n_in,
                              void* d_out, int out_size, void* d_ws, size_t ws_size,
                              hipStream_t stream) {
    const float* feat = (const float*)d_in[0];
    const float* W    = (const float*)d_in[1];
    const int*   et   = (const int*)d_in[2];
    const int*   src  = (const int*)d_in[3];
    const int*   dst  = (const int*)d_in[4];
    float* out = (float*)d_out;

    const int N = in_sizes[0] / D;
    const int R = in_sizes[1] / (D * D);
    const int E = in_sizes[2];

    size_t hB   = al256((size_t)R * N * D * sizeof(unsigned short));
    size_t wtB  = al256((size_t)R * D * D * sizeof(unsigned short));
    size_t offB = al256((size_t)(N + 1) * sizeof(int));
    size_t degB = al256((size_t)N * sizeof(int));
    size_t ordB = al256((size_t)E * sizeof(int));
    size_t parB = al256(1024 * sizeof(int));
    size_t srtB = al256((size_t)E * sizeof(unsigned int));
    size_t fbB  = al256((size_t)N * D * sizeof(unsigned short));
    size_t need = hB + wtB + offB + degB + ordB + parB + srtB + fbB;

    const int nbScan = (N + 255) / 256;
    const bool packable = (nbScan <= 256) &&
                          ((size_t)R * (size_t)N * 256ull <= 0xFFFFFFFFull);

    if (ws_size >= need && packable) {
        char* p = (char*)d_ws;
        unsigned short* H      = (unsigned short*)p;           p += hB;
        unsigned short* Wt     = (unsigned short*)p;           p += wtB;
        int*            off    = (int*)p;                      p += offB;
        int*            deg    = (int*)p;                      p += degB;
        int*            ord    = (int*)p;                      p += ordB;
        int*            part   = (int*)p;                      p += parB;
        unsigned int*   sorted = (unsigned int*)p;             p += srtB;
        unsigned short* featb  = (unsigned short*)p;

        int wtTotal = R * D * D;
        int fcTotal = (N * D) / 8;
        int fcBlocks = (fcTotal + 255) / 256;
        int wtBlocks = (wtTotal + 255) / 256;
        int cntBlocks = (E + 255) / 256;

        hipMemsetAsync(deg, 0, (size_t)N * sizeof(int), stream);
        prep2_kernel<<<fcBlocks + wtBlocks, 256, 0, stream>>>(
            feat, featb, W, Wt, fcTotal, wtTotal);

        // Fused transform + count, interleaved roles
        int NBX = (N + 127) / 128;
        int tBlocks = NBX * R;
        fused2_kernel<<<tBlocks + cntBlocks, 256, 0, stream>>>(
            featb, Wt, H, dst, deg, ord, N, NBX, tBlocks, cntBlocks, E);

        // CSR build (by dst)
        k_blocksum<<<nbScan, 256, 0, stream>>>(deg, part, N);
        k_scanpart<<<1, 256, 0, stream>>>(part, nbScan);
        k_scanfinal<<<nbScan, 256, 0, stream>>>(deg, part, off, N, E);
        k_fill<<<cntBlocks, 256, 0, stream>>>(dst, et, src, off, ord, sorted, E, N);

        // Phase 2: gather-sum, 1 node/wave, 8-B lanes, 32-edge pipeline
        k_gather5<<<(N + 3) / 4, 256, 0, stream>>>((const char*)H, sorted, off, feat, out, N);
    } else {
        int n4 = (N * D) / 4;
        init_kernel<<<(n4 + 255) / 256, 256, 0, stream>>>(feat, out, n4);
        edge_matvec_kernel<<<E, 128, 0, stream>>>(feat, W, et, src, dst, out, E);
    }
}

// Round 10
// 176.428 us; speedup vs baseline: 1.1439x; 1.0137x over previous
//
#include <hip/hip_runtime.h>
#include <hip/hip_bf16.h>
#include <stdint.h>

#define D 128
#define CAP 48        // fixed per-node slot capacity (Poisson(12.8): P(deg>48)~1e-13)
#define OVFCAP 65536

using bf16x8 = __attribute__((ext_vector_type(8))) short;
using f32x4  = __attribute__((ext_vector_type(4))) float;

__device__ __forceinline__ unsigned short f2bf(float f) {
    unsigned u = __float_as_uint(f);
    u = (u + 0x7fffu + ((u >> 16) & 1u)) >> 16;   // RNE
    return (unsigned short)u;
}
__device__ __forceinline__ float bf2f(unsigned short h) {
    return __uint_as_float(((unsigned)h) << 16);
}

__device__ __forceinline__ bf16x8 cvt8(float4 a, float4 b) {
    union { bf16x8 v; __hip_bfloat162 h[4]; } u;
    u.h[0] = __float22bfloat162_rn(make_float2(a.x, a.y));
    u.h[1] = __float22bfloat162_rn(make_float2(a.z, a.w));
    u.h[2] = __float22bfloat162_rn(make_float2(b.x, b.y));
    u.h[3] = __float22bfloat162_rn(make_float2(b.z, b.w));
    return u.v;
}

__device__ __forceinline__ uint4 pack2(f32x4 x, f32x4 y) {
    union { uint4 u; __hip_bfloat162 h[4]; } o;
    o.h[0] = __float22bfloat162_rn(make_float2(x[0], x[1]));
    o.h[1] = __float22bfloat162_rn(make_float2(x[2], x[3]));
    o.h[2] = __float22bfloat162_rn(make_float2(y[0], y[1]));
    o.h[3] = __float22bfloat162_rn(make_float2(y[2], y[3]));
    return o.u;
}

// ---------- prep3: zero deg/ovfcnt + featb cast + Wt transpose ----------
__global__ __launch_bounds__(256) void prep3_kernel(
    const float* __restrict__ feat, unsigned short* __restrict__ featb,
    const float* __restrict__ W, unsigned short* __restrict__ Wt,
    int* __restrict__ deg /* N+1 ints: deg[N] = ovf counter */,
    int N, int fcTotal /*chunks of 8*/, int wtTotal)
{
    int zBlocks  = (N + 1 + 255) >> 8;
    int fcBlocks = (fcTotal + 255) >> 8;
    int b = blockIdx.x;
    if (b < zBlocks) {
        int i = b * 256 + threadIdx.x;
        if (i <= N) deg[i] = 0;
    } else if (b < zBlocks + fcBlocks) {
        int i = (b - zBlocks) * 256 + threadIdx.x;
        if (i < fcTotal) {
            const float4* p = (const float4*)feat + (size_t)i * 2;
            *(bf16x8*)(featb + (size_t)i * 8) = cvt8(p[0], p[1]);
        }
    } else {
        int idx = (b - zBlocks - fcBlocks) * 256 + threadIdx.x;
        if (idx < wtTotal) {
            int r = idx >> 14;
            int rem = idx & 16383;
            int k = rem >> 7, c = rem & 127;
            Wt[(r << 14) + (c << 7) + k] = f2bf(W[idx]);
        }
    }
}

// ---------- fused3: transform + count&slot-write, Bresenham-interleaved ----------
// transform: H[r][n][perm(c)] = bf16(featb[n][:] @ W[r]); Wt[rel] in
// XOR-swizzled LDS (one barrier), conflict-free ds_read_b128, permuted
// sector-aligned uint4 stores.
// count: ord = atomicAdd(deg[dst]); slots[dst*CAP+ord] = H-row byte offset.
// No scan, no fill — gather indexes slots directly.
__global__ __launch_bounds__(256) void fused3_kernel(
    const unsigned short* __restrict__ featb, const unsigned short* __restrict__ Wt,
    unsigned short* __restrict__ H,
    const int* __restrict__ dst, const int* __restrict__ et,
    const int* __restrict__ src,
    int* __restrict__ deg, unsigned int* __restrict__ slots,
    int* __restrict__ ovf,
    int N, int NBX, int tBlocks, int cntBlocks, int E)
{
    __shared__ __align__(16) unsigned short sW[128 * 128];   // 32 KB
    const int b = blockIdx.x;
    const long long total = (long long)tBlocks + cntBlocks;

    long long cb = ((long long)b * cntBlocks) / total;
    bool isCount = (((long long)(b + 1) * cntBlocks) / total) > cb;

    if (isCount) {
        int e = (int)cb * 256 + threadIdx.x;
        if (e < E) {
            int d = dst[e];
            unsigned key = ((unsigned)et[e] * (unsigned)N + (unsigned)src[e]) << 8;
            int ord = atomicAdd(&deg[d], 1);
            if (ord < CAP) {
                slots[(size_t)d * CAP + ord] = key;
            } else {
                int o = atomicAdd(&deg[N], 1);   // overflow counter
                if (o < OVFCAP) ovf[o] = e;
            }
        }
        return;
    }

    const int tIdx = b - (int)cb;
    const int rel = tIdx / NBX;
    const int bx  = tIdx - rel * NBX;
    const int tid  = threadIdx.x;
    const int wave = tid >> 6, lane = tid & 63;
    const int q    = lane >> 4, mlo = lane & 15;

    // stage Wt[rel] -> LDS, swizzled: row c, 16B chunk ch at (ch ^ (c&15))
    {
        const ulonglong2* wsrc = (const ulonglong2*)(Wt + ((size_t)rel << 14));
        #pragma unroll
        for (int i = 0; i < 8; ++i) {
            int idx = tid + 256 * i;           // 0..2047
            int row = idx >> 4, ch = idx & 15;
            ulonglong2 v = wsrc[idx];
            *(ulonglong2*)&sW[row * 128 + ((ch ^ (row & 15)) * 8)] = v;
        }
    }

    // B-frags: 2 groups of 16 nodes; B[k=ks*32+q*8+j][n=mlo]
    const int nb = bx * 128 + wave * 32;
    bf16x8 bfr[2][4];
    int nodeg[2];
    #pragma unroll
    for (int g = 0; g < 2; ++g) {
        int node = nb + g * 16 + mlo;
        nodeg[g] = node;
        int ld = node < N ? node : N - 1;
        const unsigned short* fp = featb + (size_t)ld * D + q * 8;
        #pragma unroll
        for (int ks = 0; ks < 4; ++ks)
            bfr[g][ks] = *(const bf16x8*)(fp + ks * 32);
    }
    __syncthreads();

    const size_t Hb = (size_t)rel * N * D;
    unsigned short* hp0 = H + Hb + (size_t)nodeg[0] * D + q * 8;
    unsigned short* hp1 = H + Hb + (size_t)nodeg[1] * D + q * 8;

    #pragma unroll
    for (int j = 0; j < 4; ++j) {
        bf16x8 af0[4], af1[4];
        const int row0 = (2 * j) * 16 + mlo, row1 = row0 + 16;
        #pragma unroll
        for (int ks = 0; ks < 4; ++ks) {
            af0[ks] = *(const bf16x8*)&sW[row0 * 128 + (((ks * 4 + q) ^ mlo) * 8)];
            af1[ks] = *(const bf16x8*)&sW[row1 * 128 + (((ks * 4 + q) ^ mlo) * 8)];
        }
        #pragma unroll
        for (int g = 0; g < 2; ++g) {
            f32x4 a = {0.f,0.f,0.f,0.f}, c = {0.f,0.f,0.f,0.f};
            #pragma unroll
            for (int ks = 0; ks < 4; ++ks) {
                a = __builtin_amdgcn_mfma_f32_16x16x32_bf16(af0[ks], bfr[g][ks], a, 0, 0, 0);
                c = __builtin_amdgcn_mfma_f32_16x16x32_bf16(af1[ks], bfr[g][ks], c, 0, 0, 0);
            }
            if (nodeg[g] < N)
                *(uint4*)((g ? hp1 : hp0) + j * 32) = pack2(a, c);
        }
    }
}

// ---------- gather: 1 node/wave; slots indexed directly (j0 = n*CAP);
// 8-B lane loads (32 lanes/row, halves take even/odd edges); combine via
// shfl(lane^32); channel map matches transform's permuted H layout. ----------
__global__ __launch_bounds__(256) void k_gather6(
    const char* __restrict__ Hc, const unsigned int* __restrict__ slots,
    const int* __restrict__ deg, const float* __restrict__ feat,
    float* __restrict__ out, int N)
{
    int n = blockIdx.x * 4 + (threadIdx.x >> 6);
    if (n >= N) return;
    int lane = threadIdx.x & 63;
    int h = lane >> 5, l5 = lane & 31;

    float2 acc0 = {0.f, 0.f}, acc1 = {0.f, 0.f};

    int dg = deg[n];
    dg = __builtin_amdgcn_readfirstlane(dg);
    int capped = dg < CAP ? dg : CAP;
    if (capped > 0) {
        unsigned ep = slots[(size_t)n * CAP + (lane < capped ? lane : capped - 1)];
        for (int done = 0; done < capped; done += 32) {
            unsigned long long a[16];
            #pragma unroll
            for (int u = 0; u < 16; ++u) {
                int eidx = done + 2 * u + h;
                int cl = eidx < capped ? eidx : capped - 1;
                unsigned p = __shfl(ep, cl);
                a[u] = *(const unsigned long long*)(Hc + p + l5 * 8);
            }
            #pragma unroll
            for (int u = 0; u < 16; ++u) {
                bool v = (done + 2 * u + h) < capped;
                unsigned lo = (unsigned)a[u], hi = (unsigned)(a[u] >> 32);
                acc0.x += v ? bf2f((unsigned short)(lo & 0xffffu)) : 0.f;
                acc0.y += v ? bf2f((unsigned short)(lo >> 16)) : 0.f;
                acc1.x += v ? bf2f((unsigned short)(hi & 0xffffu)) : 0.f;
                acc1.y += v ? bf2f((unsigned short)(hi >> 16)) : 0.f;
            }
        }
    }
    // combine halves
    acc0.x += __shfl(acc0.x, lane ^ 32);
    acc0.y += __shfl(acc0.y, lane ^ 32);
    acc1.x += __shfl(acc1.x, lane ^ 32);
    acc1.y += __shfl(acc1.y, lane ^ 32);
    if (h == 0) {
        int f4 = 8 * (l5 >> 3) + 4 * (l5 & 1) + ((l5 >> 1) & 3);
        float4 fv = ((const float4*)feat)[(size_t)n * 32 + f4];
        float4 o;
        o.x = fv.x + acc0.x; o.y = fv.y + acc0.y;
        o.z = fv.z + acc1.x; o.w = fv.w + acc1.y;
        ((float4*)out)[(size_t)n * 32 + f4] = o;
    }
}

// ---------- overflow scatter (normally 0 work; correctness for deg>CAP) ----------
__global__ __launch_bounds__(256) void k_ovf(
    const char* __restrict__ Hc, const int* __restrict__ ovf,
    const int* __restrict__ deg /* deg[N] = count */,
    const int* __restrict__ dst, const int* __restrict__ et,
    const int* __restrict__ src, float* __restrict__ out, int N)
{
    int cnt = deg[N];
    if (cnt > OVFCAP) cnt = OVFCAP;
    int wid = (blockIdx.x * 256 + threadIdx.x) >> 6;
    int nw = (gridDim.x * 256) >> 6;
    int lane = threadIdx.x & 63;
    const int jj = lane >> 4, qq = (lane >> 2) & 3, pp = lane & 3;
    const int f = 16 * jj + 8 * (pp >> 1) + 2 * qq + (pp & 1);
    for (int i = wid; i < cnt; i += nw) {
        int e = ovf[i];
        int d = dst[e];
        unsigned key = ((unsigned)et[e] * (unsigned)N + (unsigned)src[e]) << 8;
        unsigned a = *(const unsigned*)(Hc + key + lane * 4);
        atomicAdd(out + (size_t)d * D + 2 * f,     bf2f((unsigned short)(a & 0xffffu)));
        atomicAdd(out + (size_t)d * D + 2 * f + 1, bf2f((unsigned short)(a >> 16)));
    }
}

// ---------- fallbacks ----------
__global__ __launch_bounds__(256) void init_kernel(
    const float* __restrict__ feat, float* __restrict__ out, int n4)
{
    int i = blockIdx.x * 256 + threadIdx.x;
    if (i < n4) ((float4*)out)[i] = ((const float4*)feat)[i];
}

__global__ __launch_bounds__(128) void edge_matvec_kernel(
    const float* __restrict__ feat, const float* __restrict__ W,
    const int* __restrict__ et, const int* __restrict__ src,
    const int* __restrict__ dst, float* __restrict__ out, int E)
{
    __shared__ float xs[D];
    int e = blockIdx.x;
    int c = threadIdx.x;
    int s = src[e], r = et[e], d = dst[e];
    xs[c] = feat[(size_t)s * D + c];
    __syncthreads();
    const float* Wr = W + (size_t)r * D * D;
    float acc = 0.f;
    #pragma unroll 8
    for (int k = 0; k < D; ++k) acc += xs[k] * Wr[(size_t)k * D + c];
    atomicAdd(out + (size_t)d * D + c, acc);
}

static inline size_t al256(size_t x) { return (x + 255) & ~(size_t)255; }

extern "C" void kernel_launch(void* const* d_in, const int* in_sizes, int n_in,
                              void* d_out, int out_size, void* d_ws, size_t ws_size,
                              hipStream_t stream) {
    const float* feat = (const float*)d_in[0];
    const float* W    = (const float*)d_in[1];
    const int*   et   = (const int*)d_in[2];
    const int*   src  = (const int*)d_in[3];
    const int*   dst  = (const int*)d_in[4];
    float* out = (float*)d_out;

    const int N = in_sizes[0] / D;
    const int R = in_sizes[1] / (D * D);
    const int E = in_sizes[2];

    size_t hB   = al256((size_t)R * N * D * sizeof(unsigned short));
    size_t wtB  = al256((size_t)R * D * D * sizeof(unsigned short));
    size_t degB = al256((size_t)(N + 1) * sizeof(int));
    size_t sltB = al256((size_t)N * CAP * sizeof(unsigned int));
    size_t ovfB = al256((size_t)OVFCAP * sizeof(int));
    size_t fbB  = al256((size_t)N * D * sizeof(unsigned short));
    size_t need = hB + wtB + degB + sltB + ovfB + fbB;

    const bool packable = ((size_t)R * (size_t)N * 256ull <= 0xFFFFFFFFull);

    if (ws_size >= need && packable) {
        char* p = (char*)d_ws;
        unsigned short* H      = (unsigned short*)p;           p += hB;
        unsigned short* Wt     = (unsigned short*)p;           p += wtB;
        int*            deg    = (int*)p;                      p += degB;
        unsigned int*   slots  = (unsigned int*)p;             p += sltB;
        int*            ovf    = (int*)p;                      p += ovfB;
        unsigned short* featb  = (unsigned short*)p;

        int wtTotal = R * D * D;
        int fcTotal = (N * D) / 8;
        int zBlocks  = (N + 1 + 255) / 256;
        int fcBlocks = (fcTotal + 255) / 256;
        int wtBlocks = (wtTotal + 255) / 256;
        int cntBlocks = (E + 255) / 256;

        prep3_kernel<<<zBlocks + fcBlocks + wtBlocks, 256, 0, stream>>>(
            feat, featb, W, Wt, deg, N, fcTotal, wtTotal);

        int NBX = (N + 127) / 128;
        int tBlocks = NBX * R;
        fused3_kernel<<<tBlocks + cntBlocks, 256, 0, stream>>>(
            featb, Wt, H, dst, et, src, deg, slots, ovf,
            N, NBX, tBlocks, cntBlocks, E);

        k_gather6<<<(N + 3) / 4, 256, 0, stream>>>(
            (const char*)H, slots, deg, feat, out, N);

        k_ovf<<<16, 256, 0, stream>>>(
            (const char*)H, ovf, deg, dst, et, src, out, N);
    } else {
        int n4 = (N * D) / 4;
        init_kernel<<<(n4 + 255) / 256, 256, 0, stream>>>(feat, out, n4);
        edge_matvec_kernel<<<E, 128, 0, stream>>>(feat, W, et, src, dst, out, E);
    }
}